// Round 14
// baseline (619.557 us; speedup 1.0000x reference)
//
#include <hip/hip_runtime.h>
#include <math.h>

#define BATCH 8
#define C 64
#define NH 8
#define HD 8
#define LTXT 77
#define H0 64
#define W0 64
#define HW0 (H0*W0)

typedef __attribute__((ext_vector_type(8))) short bfrag;    // 8 bf16 (4 VGPR)
typedef __attribute__((ext_vector_type(4))) float ffrag;    // 4 fp32 acc
typedef __attribute__((ext_vector_type(8))) unsigned short us8;
typedef __attribute__((ext_vector_type(4))) unsigned short us4;
typedef __attribute__((ext_vector_type(2))) float f2;

__device__ __forceinline__ unsigned short f2bf(float f) {
    unsigned u = __builtin_bit_cast(unsigned, f);
    u += 0x7fff + ((u >> 16) & 1);   // RNE
    return (unsigned short)(u >> 16);
}

// ---------------- text projection: tf[b,l,c] = th[b,l,:] . proj_w[c,:] + proj_b[c]
__global__ void text_proj_kernel(const float* __restrict__ th, const float* __restrict__ pw,
                                 const float* __restrict__ pb, float* __restrict__ tf) {
    __shared__ float sh[512];
    int bl = blockIdx.x;
    int c = threadIdx.x;
    const float* row = th + (size_t)bl * 512;
    for (int i = c; i < 512; i += 64) sh[i] = row[i];
    __syncthreads();
    const float* wrow = pw + c * 512;
    float acc = pb[c];
    for (int i = 0; i < 512; i += 4) {
        acc += sh[i] * wrow[i] + sh[i+1] * wrow[i+1] + sh[i+2] * wrow[i+2] + sh[i+3] * wrow[i+3];
    }
    tf[bl * 64 + c] = acc;
}

// ---------------- merged prep: conv_in (blocks 0..8191) + pack_up (8192..9343)
// + pack_final (9344..9379) + pack_proj (9380..9635)
__global__ void __launch_bounds__(256)
prep_kernel(const float* __restrict__ x, const float* __restrict__ cf_w,
            const float* __restrict__ cf_b, float* __restrict__ feat,
            const float* __restrict__ up_w,
            unsigned short* __restrict__ PW1, unsigned short* __restrict__ PW2,
            const float* __restrict__ cl_w, unsigned short* __restrict__ PWF,
            const float* __restrict__ qw, const float* __restrict__ ow,
            unsigned short* __restrict__ PQ, unsigned short* __restrict__ PO) {
    int blk = blockIdx.x;
    if (blk < 8192) {
        // conv_in: x[8,3,64,64] -> feat[8,64,64,64] fp32 NCHW
        int idx = blk * 256 + threadIdx.x;
        int wx = idx & 63;
        int h = (idx >> 6) & 63;
        int o = (idx >> 12) & 63;
        int b = idx >> 18;
        const float* wr = cf_w + o * 27;
        float acc = cf_b[o];
        for (int ci = 0; ci < 3; ci++) {
            for (int ky = 0; ky < 3; ky++) {
                int y = h + ky - 1;
                if ((unsigned)y >= 64u) continue;
                const float* xr = x + (((size_t)b * 3 + ci) * 64 + y) * 64;
                const float* wk = wr + ci * 9 + ky * 3;
                if (wx > 0) acc += xr[wx - 1] * wk[0];
                acc += xr[wx] * wk[1];
                if (wx < 63) acc += xr[wx + 1] * wk[2];
            }
        }
        feat[idx] = acc;
    } else if (blk < 8192 + 1152) {
        int e0 = blk - 8192;
        int st = e0 / 576;
        int e = (e0 % 576) * 256 + threadIdx.x;   // < 147456
        const float* w = up_w + (size_t)st * 147456;
        unsigned short* d = st ? PW2 : PW1;
        int j = e & 7, n = (e >> 3) & 255, q = (e >> 11) & 3, s = (e >> 13) & 1, t = e >> 14;
        int c = n & 63, g = n >> 6;
        int co = 4 * c + g, ci = 32 * s + 8 * q + j;
        d[e] = f2bf(w[co * 576 + ci * 9 + t]);
    } else if (blk < 8192 + 1152 + 36) {
        int e = (blk - 8192 - 1152) * 256 + threadIdx.x;   // < 9216
        int j = e & 7, n = (e >> 3) & 15, q = (e >> 7) & 3, s = (e >> 9) & 1, t = e >> 10;
        int ci = 32 * s + 8 * q + j;
        float v = (n < 3) ? cl_w[n * 576 + ci * 9 + t] : 0.f;
        PWF[e] = f2bf(v);
    } else {
        int e = (blk - 8192 - 1152 - 36) * 256 + threadIdx.x;   // < 65536
        int j = e & 7, n = (e >> 3) & 63, quad = (e >> 9) & 3, kt = (e >> 11) & 1, layer = e >> 12;
        int c = kt * 32 + quad * 8 + j;
        PQ[e] = f2bf(qw[layer * 4096 + n * 64 + c]);
        PO[e] = f2bf(ow[layer * 4096 + n * 64 + c]);
    }
}

// ---------------- K/V for ALL 16 blocks upfront; K pre-scaled by scale*log2(e)
__global__ void kv_all_kernel(const float* __restrict__ tf,
                              const float* __restrict__ kw, const float* __restrict__ kb,
                              const float* __restrict__ vw, const float* __restrict__ vb,
                              const float* __restrict__ l2w, const float* __restrict__ l2b,
                              float* __restrict__ kbuf, float* __restrict__ vbuf) {
    __shared__ float sh[64];
    int g = blockIdx.x;
    int bl = g % (BATCH * LTXT);
    int blk = g / (BATCH * LTXT);
    int o = threadIdx.x;
    sh[o] = tf[bl * 64 + o];
    __syncthreads();
    const float* kr = kw + blk * 4096 + o * 64;
    const float* vr = vw + blk * 4096 + o * 64;
    float ka = kb[blk * 64 + o], va = vb[blk * 64 + o];
    for (int c2 = 0; c2 < 64; c2++) {
        float t = sh[c2];
        ka += t * kr[c2];
        va += t * vr[c2];
    }
    float s = ka;
    for (int off = 32; off; off >>= 1) s += __shfl_xor(s, off, 64);
    float mean = s * (1.0f / 64.0f);
    float d = ka - mean;
    float s2 = d * d;
    for (int off = 32; off; off >>= 1) s2 += __shfl_xor(s2, off, 64);
    float rstd = rsqrtf(s2 * (1.0f / 64.0f) + 1e-5f);
    size_t outi = (size_t)blk * (BATCH * LTXT * 64) + (size_t)bl * 64 + o;
    kbuf[outi] = (d * rstd * l2w[blk * 64 + o] + l2b[blk * 64 + o]) * 0.51006973f;
    vbuf[outi] = va;
}

// ---------------- ALL 16 attention blocks fused, 1024 threads = 16 waves.
__global__ void __launch_bounds__(1024, 8)
attn_all_kernel(const float* __restrict__ feat,
                const float* __restrict__ kbuf, const float* __restrict__ vbuf,
                const unsigned short* __restrict__ PQ, const unsigned short* __restrict__ PO,
                const float* __restrict__ qb_a, const float* __restrict__ ob_a,
                const float* __restrict__ l1w_a, const float* __restrict__ l1b_a,
                unsigned short* __restrict__ X1) {
    __shared__ __attribute__((aligned(16))) unsigned short sfb[64][72]; // residual bf16 [p][c]
    __shared__ __attribute__((aligned(16))) unsigned short sob[64][72]; // attn-out bf16 [p][c]
    __shared__ __attribute__((aligned(16))) float qf[64][68];           // raw q / out-proj [c][p]
    __shared__ float so[64][64];        // half-1 raw acc exchange [c][p]
    __shared__ __attribute__((aligned(16))) float red[2][4][64];        // LN partials [s][nt][p]
    __shared__ float ss1[8][64];        // half-1 softmax denominators

    int b = blockIdx.x >> 6;
    int tile = blockIdx.x & 63;
    int n0 = tile << 6;
    int wv = __builtin_amdgcn_readfirstlane(threadIdx.x >> 6);  // wave 0..15
    int lane = threadIdx.x & 63;
    int p = lane;
    int quad = lane >> 4, n16 = lane & 15;
    int mt = wv >> 2, nt = wv & 3;      // GEMM C-tile role
    int o0 = wv * 4;                    // ownership role: channels o0..o0+3, pixel p
    int h = wv >> 1, half = wv & 1;     // attention role
    int a0 = h * 8;
    const float* fbase = feat + ((size_t)b << 18) + n0;

    // stage: residual regs + bf16 mirror
    float rres[4];
#pragma unroll
    for (int j = 0; j < 4; j++) rres[j] = fbase[(o0 + j) * HW0 + p];
    {
        us4 v;
#pragma unroll
        for (int j = 0; j < 4; j++) v[j] = f2bf(rres[j]);
        *(us4*)&sfb[p][o0] = v;
    }

    const float pxk = 0.05f / 63.0f;
    float py005 = (float)tile * pxk;
    __syncthreads();

#pragma unroll 1
    for (int layer = 0; layer < 16; layer++) {
        const float* qb = qb_a + layer * 64;
        const float* ob = ob_a + layer * 64;
        const float* l1w = l1w_a + layer * 64;
        const float* l1b = l1b_a + layer * 64;

        // ---- A: q-proj GEMM + in-wave LN partial reduction in epilogue
        {
            bfrag af0 = *(const bfrag*)&sfb[mt * 16 + n16][quad * 8];
            bfrag af1 = *(const bfrag*)&sfb[mt * 16 + n16][32 + quad * 8];
            const unsigned short* bq = PQ + layer * 4096 + (size_t)((quad * 64) + nt * 16 + n16) * 8;
            bfrag bf0 = *(const bfrag*)bq;
            bfrag bf1 = *(const bfrag*)(bq + 2048);   // kt=1 chunk
            ffrag cc = (ffrag)0.f;
            cc = __builtin_amdgcn_mfma_f32_16x16x32_bf16(af0, bf0, cc, 0, 0, 0);
            cc = __builtin_amdgcn_mfma_f32_16x16x32_bf16(af1, bf1, cc, 0, 0, 0);
            int cch = nt * 16 + n16;
            float qbv = qb[cch];
            int p0 = mt * 16 + quad * 4;
            float pe0 = (nt < 2) ? (float)p0 * pxk : py005;
            float ped = (nt < 2) ? pxk : 0.f;
            float ov[4];
            ov[0] = cc[0] + qbv + pe0;
            ov[1] = cc[1] + qbv + pe0 + ped;
            ov[2] = cc[2] + qbv + pe0 + 2.f * ped;
            ov[3] = cc[3] + qbv + pe0 + 3.f * ped;
            float4 o4 = {ov[0], ov[1], ov[2], ov[3]};
            *(float4*)&qf[cch][p0] = o4;

            // channel-sum over the 16 n16 lanes (same quad), per pixel r
            float sv[4], sq[4];
#pragma unroll
            for (int r = 0; r < 4; r++) {
                float s = ov[r], s2v = ov[r] * ov[r];
                s += __shfl_xor(s, 1);  s2v += __shfl_xor(s2v, 1);
                s += __shfl_xor(s, 2);  s2v += __shfl_xor(s2v, 2);
                s += __shfl_xor(s, 4);  s2v += __shfl_xor(s2v, 4);
                s += __shfl_xor(s, 8);  s2v += __shfl_xor(s2v, 8);
                sv[r] = s; sq[r] = s2v;
            }
            if (n16 == 0) {
                *(float4*)&red[0][nt][p0] = (float4){sv[0], sv[1], sv[2], sv[3]};
                *(float4*)&red[1][nt][p0] = (float4){sq[0], sq[1], sq[2], sq[3]};
            }
        }
        __syncthreads();   // B1

        // ---- C: attention, wave = (head, token-half); stats + normalize inline
        {
            float ts = red[0][0][p] + red[0][1][p] + red[0][2][p] + red[0][3][p];
            float ts2 = red[1][0][p] + red[1][1][p] + red[1][2][p] + red[1][3][p];
            float mean = ts * (1.0f / 64.0f);
            float var = ts2 * (1.0f / 64.0f) - mean * mean;
            float rstd = rsqrtf(var + 1e-5f);

            f2 qv[4];
#pragma unroll
            for (int j = 0; j < 4; j++) {
                float qa  = (qf[a0 + 2 * j][p]     - mean) * rstd * l1w[a0 + 2 * j]     + l1b[a0 + 2 * j];
                float qbv = (qf[a0 + 2 * j + 1][p] - mean) * rstd * l1w[a0 + 2 * j + 1] + l1b[a0 + 2 * j + 1];
                qv[j][0] = qa;
                qv[j][1] = qbv;
            }
            const float* kb_b = kbuf + ((size_t)layer * BATCH * LTXT + (size_t)b * LTXT) * 64 + a0;
            const float* vb_b = vbuf + ((size_t)layer * BATCH * LTXT + (size_t)b * LTXT) * 64 + a0;
            float ssum = 0.f;
            f2 acc2[4] = {(f2)0.f, (f2)0.f, (f2)0.f, (f2)0.f};

            auto tok = [&](int l) {
                const float4* kr = (const float4*)(kb_b + l * 64);   // wave-uniform -> s_load
                float4 k0 = kr[0], k1 = kr[1];
                f2 d2 = qv[0] * (f2){k0.x, k0.y};
                d2 += qv[1] * (f2){k0.z, k0.w};
                d2 += qv[2] * (f2){k1.x, k1.y};
                d2 += qv[3] * (f2){k1.z, k1.w};
                float e = exp2f(d2[0] + d2[1]);
                ssum += e;
                const float4* vr = (const float4*)(vb_b + l * 64);   // wave-uniform -> s_load
                float4 v0 = vr[0], v1 = vr[1];
                f2 e2 = {e, e};
                acc2[0] += e2 * (f2){v0.x, v0.y};
                acc2[1] += e2 * (f2){v0.z, v0.w};
                acc2[2] += e2 * (f2){v1.x, v1.y};
                acc2[3] += e2 * (f2){v1.z, v1.w};
            };
            // compile-time trip counts -> compiler can unroll & batch s_loads
            if (half) {
#pragma unroll 4
                for (int l = 39; l < 77; l++) tok(l);
            } else {
#pragma unroll 4
                for (int l = 0; l < 39; l++) tok(l);
            }

            if (half) {
#pragma unroll
                for (int j = 0; j < 4; j++) {
                    so[a0 + 2 * j][p] = acc2[j][0];
                    so[a0 + 2 * j + 1][p] = acc2[j][1];
                }
                ss1[h][p] = ssum;
            }
            __syncthreads();   // B4
            if (!half) {
                float inv = 1.0f / (ssum + ss1[h][p]);
                us8 v;
#pragma unroll
                for (int j = 0; j < 4; j++) {
                    v[2*j]   = f2bf((acc2[j][0] + so[a0 + 2*j][p]) * inv);
                    v[2*j+1] = f2bf((acc2[j][1] + so[a0 + 2*j+1][p]) * inv);
                }
                *(us8*)&sob[p][a0] = v;
            }
        }
        __syncthreads();   // B5

        // ---- D: out-proj GEMM (A from sob), result -> qf (reused as scratch)
        {
            bfrag af0 = *(const bfrag*)&sob[mt * 16 + n16][quad * 8];
            bfrag af1 = *(const bfrag*)&sob[mt * 16 + n16][32 + quad * 8];
            const unsigned short* bo = PO + layer * 4096 + (size_t)((quad * 64) + nt * 16 + n16) * 8;
            bfrag bf0 = *(const bfrag*)bo;
            bfrag bf1 = *(const bfrag*)(bo + 2048);
            ffrag cc = (ffrag)0.f;
            cc = __builtin_amdgcn_mfma_f32_16x16x32_bf16(af0, bf0, cc, 0, 0, 0);
            cc = __builtin_amdgcn_mfma_f32_16x16x32_bf16(af1, bf1, cc, 0, 0, 0);
            int cch = nt * 16 + n16;
            float obv = ob[cch];
            int p0 = mt * 16 + quad * 4;
            float4 o4;
            o4.x = cc[0] + obv; o4.y = cc[1] + obv; o4.z = cc[2] + obv; o4.w = cc[3] + obv;
            *(float4*)&qf[cch][p0] = o4;
        }
        __syncthreads();   // B6

        // ---- E: residual update in regs + refresh bf16 mirror
        {
            us4 v;
#pragma unroll
            for (int j = 0; j < 4; j++) {
                rres[j] += qf[o0 + j][p];
                v[j] = f2bf(rres[j]);
            }
            *(us4*)&sfb[p][o0] = v;
        }
        __syncthreads();   // B7
    }

    // final write: NHWC bf16
    us4 v;
#pragma unroll
    for (int j = 0; j < 4; j++) v[j] = f2bf(rres[j]);
    *(us4*)(X1 + ((size_t)(b * 4096 + n0 + p)) * 64 + o0) = v;
}

// ---------------- upsample conv as 9-tap implicit GEMM, MFMA 16x16x32 bf16
// LDS-staged input rows; co-split x2 via blockIdx.y (n'-half) for occupancy.
__global__ void __launch_bounds__(256)
upconv_mfma_kernel(const unsigned short* __restrict__ X, const unsigned short* __restrict__ Bp,
                   const float* __restrict__ bias, unsigned short* __restrict__ Y,
                   int Hin, int Win) {
    __shared__ __attribute__((aligned(16))) unsigned short sx[3 * 66 * 72];  // 28.5 KB

    int y = blockIdx.y;                 // n'-half (r1 = y)
    int wv = threadIdx.x >> 6;
    int lane = threadIdx.x & 63;
    int q = lane >> 4, n16 = lane & 15;
    int m0 = blockIdx.x * 64;
    int hw = Hin * Win;
    int b = m0 / hw, rem = m0 % hw;
    int h = rem / Win, w0 = rem % Win;
    const unsigned short* Xb = X + (size_t)b * hw * 64;

    // stage 3 rows x 66 px x 64 ch (zero halo), ch-padded to 72
    const us8 z8 = (us8)(unsigned short)0;
    for (int e = threadIdx.x; e < 1584; e += 256) {
        int ch8 = e & 7;
        int pxi = (e >> 3) % 66;
        int row = e / 528;
        int hh = h + row - 1, wp = w0 + pxi - 1;
        us8 v = z8;
        if ((unsigned)hh < (unsigned)Hin && (unsigned)wp < (unsigned)Win)
            v = *(const us8*)(Xb + ((size_t)hh * Win + wp) * 64 + ch8 * 8);
        *(us8*)&sx[row * 4752 + pxi * 72 + ch8 * 8] = v;
    }
    __syncthreads();

    ffrag acc[4][2];
#pragma unroll
    for (int i = 0; i < 4; i++)
#pragma unroll
        for (int j2 = 0; j2 < 2; j2++) acc[i][j2] = (ffrag)0.f;

    int npb = y * 128 + wv * 32;   // n' base for this wave

    for (int t = 0; t < 9; t++) {
        int dy = t / 3, dx = t % 3;
        bfrag af[4][2];
#pragma unroll
        for (int mt = 0; mt < 4; mt++) {
            const unsigned short* sp = &sx[dy * 4752 + (mt * 16 + n16 + dx) * 72 + q * 8];
            af[mt][0] = *(const bfrag*)sp;
            af[mt][1] = *(const bfrag*)(sp + 32);
        }
#pragma unroll
        for (int s = 0; s < 2; s++) {
#pragma unroll
            for (int nt = 0; nt < 2; nt++) {
                bfrag bf = *(const bfrag*)(Bp + (size_t)((((t * 2 + s) * 4 + q) * 256) + npb + nt * 16 + n16) * 8);
#pragma unroll
                for (int mt = 0; mt < 4; mt++)
                    acc[mt][nt] = __builtin_amdgcn_mfma_f32_16x16x32_bf16(af[mt][s], bf, acc[mt][nt], 0, 0, 0);
            }
        }
    }

    int g = y * 2 + (wv >> 1);         // g' = 2*r1 + r2
    int r1 = y, r2 = wv >> 1;
    int cbase = (wv & 1) * 32;
    float bv[2];
#pragma unroll
    for (int nt = 0; nt < 2; nt++) bv[nt] = bias[4 * (cbase + nt * 16 + n16) + g];
    int Wo = Win * 2;
    unsigned short* Yb = Y + ((size_t)b * Hin * 2 * Wo + (size_t)(2 * h + r1) * Wo + r2) * 64;
#pragma unroll
    for (int mt = 0; mt < 4; mt++) {
#pragma unroll
        for (int r = 0; r < 4; r++) {
            int m = mt * 16 + q * 4 + r;   // C/D: row = quad*4 + reg
            unsigned short* dst = Yb + (size_t)(2 * (w0 + m)) * 64;
#pragma unroll
            for (int nt = 0; nt < 2; nt++) {
                float v = acc[mt][nt][r] + bv[nt];
                v = fmaxf(v, 0.f);
                dst[cbase + nt * 16 + n16] = f2bf(v);
            }
        }
    }
}

// ---------------- final conv as 9-tap implicit GEMM, N=16 (3 real), fp32 NCHW out
// 2D tile: 64 px x 4 rows per block; 6 rows x 66 px staged in LDS (57 KB).
__global__ void __launch_bounds__(256)
final_mfma_kernel(const unsigned short* __restrict__ X, const unsigned short* __restrict__ Bp,
                  const float* __restrict__ bias, float* __restrict__ out) {
    __shared__ __attribute__((aligned(16))) unsigned short sx[6 * 66 * 72];  // 57 KB

    int t0 = blockIdx.x;
    int wseg = t0 & 3;
    int rg = (t0 >> 2) & 63;
    int b = t0 >> 8;
    int y0 = rg * 4, w0 = wseg * 64;
    int wv = threadIdx.x >> 6, lane = threadIdx.x & 63;
    int q = lane >> 4, n16 = lane & 15;
    const unsigned short* Xb = X + (size_t)b * 65536 * 64;

    // stage 6 rows x 66 px x 64 ch (zero halo), ch pitch 72
    const us8 z8 = (us8)(unsigned short)0;
    for (int e = threadIdx.x; e < 3168; e += 256) {
        int ch8 = e & 7;
        int pxi = (e >> 3) % 66;
        int row = e / 528;
        int hh = y0 - 1 + row, wp = w0 - 1 + pxi;
        us8 v = z8;
        if ((unsigned)hh < 256u && (unsigned)wp < 256u)
            v = *(const us8*)(Xb + ((size_t)hh * 256 + wp) * 64 + ch8 * 8);
        *(us8*)&sx[row * 4752 + pxi * 72 + ch8 * 8] = v;
    }
    __syncthreads();

    // wave wv handles row y0+wv, 64 px
    ffrag acc[4];
#pragma unroll
    for (int i = 0; i < 4; i++) acc[i] = (ffrag)0.f;

    for (int t = 0; t < 9; t++) {
        int dy = t / 3, dx = t % 3;
        bfrag af[4][2];
#pragma unroll
        for (int mt = 0; mt < 4; mt++) {
            const unsigned short* sp = &sx[(wv + dy) * 4752 + (mt * 16 + n16 + dx) * 72 + q * 8];
            af[mt][0] = *(const bfrag*)sp;
            af[mt][1] = *(const bfrag*)(sp + 32);
        }
#pragma unroll
        for (int s = 0; s < 2; s++) {
            bfrag bf = *(const bfrag*)(Bp + (size_t)((((t * 2 + s) * 4 + q) * 16) + n16) * 8);
#pragma unroll
            for (int mt = 0; mt < 4; mt++)
                acc[mt] = __builtin_amdgcn_mfma_f32_16x16x32_bf16(af[mt][s], bf, acc[mt], 0, 0, 0);
        }
    }

    if (n16 < 3) {
        float bj = bias[n16];
        float* ob = out + (((size_t)b * 3 + n16) * 256 + (y0 + wv)) * 256;
#pragma unroll
        for (int mt = 0; mt < 4; mt++)
#pragma unroll
            for (int r = 0; r < 4; r++)
                ob[w0 + mt * 16 + q * 4 + r] = acc[mt][r] + bj;
    }
}

extern "C" void kernel_launch(void* const* d_in, const int* in_sizes, int n_in,
                              void* d_out, int out_size, void* d_ws, size_t ws_size,
                              hipStream_t stream) {
    const float* x      = (const float*)d_in[0];
    const float* th     = (const float*)d_in[1];
    const float* proj_w = (const float*)d_in[2];
    const float* proj_b = (const float*)d_in[3];
    const float* cf_w   = (const float*)d_in[4];
    const float* cf_b   = (const float*)d_in[5];
    const float* qw     = (const float*)d_in[6];
    const float* qb     = (const float*)d_in[7];
    const float* kw     = (const float*)d_in[8];
    const float* kb     = (const float*)d_in[9];
    const float* vw     = (const float*)d_in[10];
    const float* vb     = (const float*)d_in[11];
    const float* ow     = (const float*)d_in[12];
    const float* ob     = (const float*)d_in[13];
    const float* l1w    = (const float*)d_in[14];
    const float* l1b    = (const float*)d_in[15];
    const float* l2w    = (const float*)d_in[16];
    const float* l2b    = (const float*)d_in[17];
    const float* up_w   = (const float*)d_in[18];
    const float* up_b   = (const float*)d_in[19];
    const float* cl_w   = (const float*)d_in[20];
    const float* cl_b   = (const float*)d_in[21];

    float* ws   = (float*)d_ws;
    float* feat = ws;                         // 2,097,152 f
    float* tf   = feat + 2097152;             // 39,424 f
    float* kbuf = tf + 39424;                 // 630,784 f
    float* vbuf = kbuf + 630784;              // 630,784 f
    unsigned short* X1  = (unsigned short*)(vbuf + 630784);  // 2,097,152 us
    unsigned short* X2  = X1 + 2097152;       // 8,388,608 us
    unsigned short* X3  = X2 + 8388608;       // 33,554,432 us
    unsigned short* PW1 = X3 + 33554432;      // 147,456 us
    unsigned short* PW2 = PW1 + 147456;       // 147,456 us
    unsigned short* PWF = PW2 + 147456;       // 9,216 us
    unsigned short* PQ  = PWF + 9216;         // 65,536 us
    unsigned short* PO  = PQ + 65536;         // 65,536 us

    hipLaunchKernelGGL(prep_kernel, dim3(8192 + 1152 + 36 + 256), dim3(256), 0, stream,
                       x, cf_w, cf_b, feat, up_w, PW1, PW2, cl_w, PWF, qw, ow, PQ, PO);
    hipLaunchKernelGGL(text_proj_kernel, dim3(BATCH * LTXT), dim3(64), 0, stream,
                       th, proj_w, proj_b, tf);
    hipLaunchKernelGGL(kv_all_kernel, dim3(16 * BATCH * LTXT), dim3(64), 0, stream,
                       tf, kw, kb, vw, vb, l2w, l2b, kbuf, vbuf);

    hipLaunchKernelGGL(attn_all_kernel, dim3(BATCH * (HW0 / 64)), dim3(1024), 0, stream,
                       feat, kbuf, vbuf, PQ, PO, qb, ob, l1w, l1b, X1);

    hipLaunchKernelGGL(upconv_mfma_kernel, dim3(BATCH * 64 * 64 / 64, 2), dim3(256), 0, stream,
                       X1, PW1, up_b, X2, 64, 64);
    hipLaunchKernelGGL(upconv_mfma_kernel, dim3(BATCH * 128 * 128 / 64, 2), dim3(256), 0, stream,
                       X2, PW2, up_b + 256, X3, 128, 128);
    hipLaunchKernelGGL(final_mfma_kernel, dim3(BATCH * 64 * 4), dim3(256), 0, stream,
                       X3, PWF, cl_b, (float*)d_out);
}

// Round 15
// 582.367 us; speedup vs baseline: 1.0639x; 1.0639x over previous
//
#include <hip/hip_runtime.h>
#include <math.h>

#define BATCH 8
#define C 64
#define NH 8
#define HD 8
#define LTXT 77
#define H0 64
#define W0 64
#define HW0 (H0*W0)

typedef __attribute__((ext_vector_type(8))) short bfrag;    // 8 bf16 (4 VGPR)
typedef __attribute__((ext_vector_type(4))) float ffrag;    // 4 fp32 acc
typedef __attribute__((ext_vector_type(8))) unsigned short us8;
typedef __attribute__((ext_vector_type(4))) unsigned short us4;
typedef __attribute__((ext_vector_type(2))) float f2;

__device__ __forceinline__ unsigned short f2bf(float f) {
    unsigned u = __builtin_bit_cast(unsigned, f);
    u += 0x7fff + ((u >> 16) & 1);   // RNE
    return (unsigned short)(u >> 16);
}

// ---------------- text projection: tf[b,l,c] = th[b,l,:] . proj_w[c,:] + proj_b[c]
__global__ void text_proj_kernel(const float* __restrict__ th, const float* __restrict__ pw,
                                 const float* __restrict__ pb, float* __restrict__ tf) {
    __shared__ float sh[512];
    int bl = blockIdx.x;
    int c = threadIdx.x;
    const float* row = th + (size_t)bl * 512;
    for (int i = c; i < 512; i += 64) sh[i] = row[i];
    __syncthreads();
    const float* wrow = pw + c * 512;
    float acc = pb[c];
    for (int i = 0; i < 512; i += 4) {
        acc += sh[i] * wrow[i] + sh[i+1] * wrow[i+1] + sh[i+2] * wrow[i+2] + sh[i+3] * wrow[i+3];
    }
    tf[bl * 64 + c] = acc;
}

// ---------------- merged prep: conv_in (blocks 0..8191) + pack_up (8192..9343)
// + pack_final (9344..9379) + pack_proj (9380..9635)
__global__ void __launch_bounds__(256)
prep_kernel(const float* __restrict__ x, const float* __restrict__ cf_w,
            const float* __restrict__ cf_b, float* __restrict__ feat,
            const float* __restrict__ up_w,
            unsigned short* __restrict__ PW1, unsigned short* __restrict__ PW2,
            const float* __restrict__ cl_w, unsigned short* __restrict__ PWF,
            const float* __restrict__ qw, const float* __restrict__ ow,
            unsigned short* __restrict__ PQ, unsigned short* __restrict__ PO) {
    int blk = blockIdx.x;
    if (blk < 8192) {
        // conv_in: x[8,3,64,64] -> feat[8,64,64,64] fp32 NCHW
        int idx = blk * 256 + threadIdx.x;
        int wx = idx & 63;
        int h = (idx >> 6) & 63;
        int o = (idx >> 12) & 63;
        int b = idx >> 18;
        const float* wr = cf_w + o * 27;
        float acc = cf_b[o];
        for (int ci = 0; ci < 3; ci++) {
            for (int ky = 0; ky < 3; ky++) {
                int y = h + ky - 1;
                if ((unsigned)y >= 64u) continue;
                const float* xr = x + (((size_t)b * 3 + ci) * 64 + y) * 64;
                const float* wk = wr + ci * 9 + ky * 3;
                if (wx > 0) acc += xr[wx - 1] * wk[0];
                acc += xr[wx] * wk[1];
                if (wx < 63) acc += xr[wx + 1] * wk[2];
            }
        }
        feat[idx] = acc;
    } else if (blk < 8192 + 1152) {
        int e0 = blk - 8192;
        int st = e0 / 576;
        int e = (e0 % 576) * 256 + threadIdx.x;   // < 147456
        const float* w = up_w + (size_t)st * 147456;
        unsigned short* d = st ? PW2 : PW1;
        int j = e & 7, n = (e >> 3) & 255, q = (e >> 11) & 3, s = (e >> 13) & 1, t = e >> 14;
        int c = n & 63, g = n >> 6;
        int co = 4 * c + g, ci = 32 * s + 8 * q + j;
        d[e] = f2bf(w[co * 576 + ci * 9 + t]);
    } else if (blk < 8192 + 1152 + 36) {
        int e = (blk - 8192 - 1152) * 256 + threadIdx.x;   // < 9216
        int j = e & 7, n = (e >> 3) & 15, q = (e >> 7) & 3, s = (e >> 9) & 1, t = e >> 10;
        int ci = 32 * s + 8 * q + j;
        float v = (n < 3) ? cl_w[n * 576 + ci * 9 + t] : 0.f;
        PWF[e] = f2bf(v);
    } else {
        int e = (blk - 8192 - 1152 - 36) * 256 + threadIdx.x;   // < 65536
        int j = e & 7, n = (e >> 3) & 63, quad = (e >> 9) & 3, kt = (e >> 11) & 1, layer = e >> 12;
        int c = kt * 32 + quad * 8 + j;
        PQ[e] = f2bf(qw[layer * 4096 + n * 64 + c]);
        PO[e] = f2bf(ow[layer * 4096 + n * 64 + c]);
    }
}

// ---------------- K/V for ALL 16 blocks upfront; K pre-scaled by scale*log2(e)
__global__ void kv_all_kernel(const float* __restrict__ tf,
                              const float* __restrict__ kw, const float* __restrict__ kb,
                              const float* __restrict__ vw, const float* __restrict__ vb,
                              const float* __restrict__ l2w, const float* __restrict__ l2b,
                              float* __restrict__ kbuf, float* __restrict__ vbuf) {
    __shared__ float sh[64];
    int g = blockIdx.x;
    int bl = g % (BATCH * LTXT);
    int blk = g / (BATCH * LTXT);
    int o = threadIdx.x;
    sh[o] = tf[bl * 64 + o];
    __syncthreads();
    const float* kr = kw + blk * 4096 + o * 64;
    const float* vr = vw + blk * 4096 + o * 64;
    float ka = kb[blk * 64 + o], va = vb[blk * 64 + o];
    for (int c2 = 0; c2 < 64; c2++) {
        float t = sh[c2];
        ka += t * kr[c2];
        va += t * vr[c2];
    }
    float s = ka;
    for (int off = 32; off; off >>= 1) s += __shfl_xor(s, off, 64);
    float mean = s * (1.0f / 64.0f);
    float d = ka - mean;
    float s2 = d * d;
    for (int off = 32; off; off >>= 1) s2 += __shfl_xor(s2, off, 64);
    float rstd = rsqrtf(s2 * (1.0f / 64.0f) + 1e-5f);
    size_t outi = (size_t)blk * (BATCH * LTXT * 64) + (size_t)bl * 64 + o;
    kbuf[outi] = (d * rstd * l2w[blk * 64 + o] + l2b[blk * 64 + o]) * 0.51006973f;
    vbuf[outi] = va;
}

// ---------------- ALL 16 attention blocks fused, 1024 threads = 16 waves.
// MFMA projections; LN partials via in-wave DPP reduction in GEMM epilogue;
// attention waves compute LN stats from 8 partials and normalize raw q inline.
// Token loop: R13-verbatim (runtime bounds, no unroll — measured-best codegen).
__global__ void __launch_bounds__(1024, 8)
attn_all_kernel(const float* __restrict__ feat,
                const float* __restrict__ kbuf, const float* __restrict__ vbuf,
                const unsigned short* __restrict__ PQ, const unsigned short* __restrict__ PO,
                const float* __restrict__ qb_a, const float* __restrict__ ob_a,
                const float* __restrict__ l1w_a, const float* __restrict__ l1b_a,
                unsigned short* __restrict__ X1) {
    __shared__ __attribute__((aligned(16))) unsigned short sfb[64][72]; // residual bf16 [p][c]
    __shared__ __attribute__((aligned(16))) unsigned short sob[64][72]; // attn-out bf16 [p][c]
    __shared__ __attribute__((aligned(16))) float qf[64][68];           // raw q / out-proj [c][p]
    __shared__ float so[64][64];        // half-1 raw acc exchange [c][p]
    __shared__ __attribute__((aligned(16))) float red[2][4][64];        // LN partials [s][nt][p]
    __shared__ float ss1[8][64];        // half-1 softmax denominators

    int b = blockIdx.x >> 6;
    int tile = blockIdx.x & 63;
    int n0 = tile << 6;
    int wv = __builtin_amdgcn_readfirstlane(threadIdx.x >> 6);  // wave 0..15
    int lane = threadIdx.x & 63;
    int p = lane;
    int quad = lane >> 4, n16 = lane & 15;
    int mt = wv >> 2, nt = wv & 3;      // GEMM C-tile role
    int o0 = wv * 4;                    // ownership role: channels o0..o0+3, pixel p
    int h = wv >> 1, half = wv & 1;     // attention role
    int a0 = h * 8;
    const float* fbase = feat + ((size_t)b << 18) + n0;

    // stage: residual regs + bf16 mirror
    float rres[4];
#pragma unroll
    for (int j = 0; j < 4; j++) rres[j] = fbase[(o0 + j) * HW0 + p];
    {
        us4 v;
#pragma unroll
        for (int j = 0; j < 4; j++) v[j] = f2bf(rres[j]);
        *(us4*)&sfb[p][o0] = v;
    }

    const float pxk = 0.05f / 63.0f;
    float py005 = (float)tile * pxk;
    __syncthreads();

#pragma unroll 1
    for (int layer = 0; layer < 16; layer++) {
        const float* qb = qb_a + layer * 64;
        const float* ob = ob_a + layer * 64;
        const float* l1w = l1w_a + layer * 64;
        const float* l1b = l1b_a + layer * 64;

        // ---- A: q-proj GEMM + in-wave LN partial reduction in epilogue
        {
            bfrag af0 = *(const bfrag*)&sfb[mt * 16 + n16][quad * 8];
            bfrag af1 = *(const bfrag*)&sfb[mt * 16 + n16][32 + quad * 8];
            const unsigned short* bq = PQ + layer * 4096 + (size_t)((quad * 64) + nt * 16 + n16) * 8;
            bfrag bf0 = *(const bfrag*)bq;
            bfrag bf1 = *(const bfrag*)(bq + 2048);   // kt=1 chunk
            ffrag cc = (ffrag)0.f;
            cc = __builtin_amdgcn_mfma_f32_16x16x32_bf16(af0, bf0, cc, 0, 0, 0);
            cc = __builtin_amdgcn_mfma_f32_16x16x32_bf16(af1, bf1, cc, 0, 0, 0);
            int cch = nt * 16 + n16;
            float qbv = qb[cch];
            int p0 = mt * 16 + quad * 4;
            float pe0 = (nt < 2) ? (float)p0 * pxk : py005;
            float ped = (nt < 2) ? pxk : 0.f;
            float ov[4];
            ov[0] = cc[0] + qbv + pe0;
            ov[1] = cc[1] + qbv + pe0 + ped;
            ov[2] = cc[2] + qbv + pe0 + 2.f * ped;
            ov[3] = cc[3] + qbv + pe0 + 3.f * ped;
            float4 o4 = {ov[0], ov[1], ov[2], ov[3]};
            *(float4*)&qf[cch][p0] = o4;

            // channel-sum over the 16 n16 lanes (same quad), per pixel r
            float sv[4], sq[4];
#pragma unroll
            for (int r = 0; r < 4; r++) {
                float s = ov[r], s2v = ov[r] * ov[r];
                s += __shfl_xor(s, 1);  s2v += __shfl_xor(s2v, 1);
                s += __shfl_xor(s, 2);  s2v += __shfl_xor(s2v, 2);
                s += __shfl_xor(s, 4);  s2v += __shfl_xor(s2v, 4);
                s += __shfl_xor(s, 8);  s2v += __shfl_xor(s2v, 8);
                sv[r] = s; sq[r] = s2v;
            }
            if (n16 == 0) {
                *(float4*)&red[0][nt][p0] = (float4){sv[0], sv[1], sv[2], sv[3]};
                *(float4*)&red[1][nt][p0] = (float4){sq[0], sq[1], sq[2], sq[3]};
            }
        }
        __syncthreads();   // B1

        // ---- C: attention, wave = (head, token-half); stats + normalize inline
        {
            float ts = red[0][0][p] + red[0][1][p] + red[0][2][p] + red[0][3][p];
            float ts2 = red[1][0][p] + red[1][1][p] + red[1][2][p] + red[1][3][p];
            float mean = ts * (1.0f / 64.0f);
            float var = ts2 * (1.0f / 64.0f) - mean * mean;
            float rstd = rsqrtf(var + 1e-5f);

            f2 qv[4];
#pragma unroll
            for (int j = 0; j < 4; j++) {
                float qa  = (qf[a0 + 2 * j][p]     - mean) * rstd * l1w[a0 + 2 * j]     + l1b[a0 + 2 * j];
                float qbv = (qf[a0 + 2 * j + 1][p] - mean) * rstd * l1w[a0 + 2 * j + 1] + l1b[a0 + 2 * j + 1];
                qv[j][0] = qa;
                qv[j][1] = qbv;
            }
            const float* kb_b = kbuf + ((size_t)layer * BATCH * LTXT + (size_t)b * LTXT) * 64 + a0;
            const float* vb_b = vbuf + ((size_t)layer * BATCH * LTXT + (size_t)b * LTXT) * 64 + a0;
            int l0 = half ? 39 : 0;
            int l1 = half ? 77 : 39;
            float ssum = 0.f;
            f2 acc2[4] = {(f2)0.f, (f2)0.f, (f2)0.f, (f2)0.f};
            for (int l = l0; l < l1; l++) {
                const float4* kr = (const float4*)(kb_b + l * 64);   // wave-uniform -> s_load
                float4 k0 = kr[0], k1 = kr[1];
                f2 d2 = qv[0] * (f2){k0.x, k0.y};
                d2 += qv[1] * (f2){k0.z, k0.w};
                d2 += qv[2] * (f2){k1.x, k1.y};
                d2 += qv[3] * (f2){k1.z, k1.w};
                float e = exp2f(d2[0] + d2[1]);
                ssum += e;
                const float4* vr = (const float4*)(vb_b + l * 64);   // wave-uniform -> s_load
                float4 v0 = vr[0], v1 = vr[1];
                f2 e2 = {e, e};
                acc2[0] += e2 * (f2){v0.x, v0.y};
                acc2[1] += e2 * (f2){v0.z, v0.w};
                acc2[2] += e2 * (f2){v1.x, v1.y};
                acc2[3] += e2 * (f2){v1.z, v1.w};
            }
            if (half) {
#pragma unroll
                for (int j = 0; j < 4; j++) {
                    so[a0 + 2 * j][p] = acc2[j][0];
                    so[a0 + 2 * j + 1][p] = acc2[j][1];
                }
                ss1[h][p] = ssum;
            }
            __syncthreads();   // B4
            if (!half) {
                float inv = 1.0f / (ssum + ss1[h][p]);
                us8 v;
#pragma unroll
                for (int j = 0; j < 4; j++) {
                    v[2*j]   = f2bf((acc2[j][0] + so[a0 + 2*j][p]) * inv);
                    v[2*j+1] = f2bf((acc2[j][1] + so[a0 + 2*j+1][p]) * inv);
                }
                *(us8*)&sob[p][a0] = v;
            }
        }
        __syncthreads();   // B5

        // ---- D: out-proj GEMM (A from sob), result -> qf (reused as scratch)
        {
            bfrag af0 = *(const bfrag*)&sob[mt * 16 + n16][quad * 8];
            bfrag af1 = *(const bfrag*)&sob[mt * 16 + n16][32 + quad * 8];
            const unsigned short* bo = PO + layer * 4096 + (size_t)((quad * 64) + nt * 16 + n16) * 8;
            bfrag bf0 = *(const bfrag*)bo;
            bfrag bf1 = *(const bfrag*)(bo + 2048);
            ffrag cc = (ffrag)0.f;
            cc = __builtin_amdgcn_mfma_f32_16x16x32_bf16(af0, bf0, cc, 0, 0, 0);
            cc = __builtin_amdgcn_mfma_f32_16x16x32_bf16(af1, bf1, cc, 0, 0, 0);
            int cch = nt * 16 + n16;
            float obv = ob[cch];
            int p0 = mt * 16 + quad * 4;
            float4 o4;
            o4.x = cc[0] + obv; o4.y = cc[1] + obv; o4.z = cc[2] + obv; o4.w = cc[3] + obv;
            *(float4*)&qf[cch][p0] = o4;
        }
        __syncthreads();   // B6

        // ---- E: residual update in regs + refresh bf16 mirror
        {
            us4 v;
#pragma unroll
            for (int j = 0; j < 4; j++) {
                rres[j] += qf[o0 + j][p];
                v[j] = f2bf(rres[j]);
            }
            *(us4*)&sfb[p][o0] = v;
        }
        __syncthreads();   // B7
    }

    // final write: NHWC bf16
    us4 v;
#pragma unroll
    for (int j = 0; j < 4; j++) v[j] = f2bf(rres[j]);
    *(us4*)(X1 + ((size_t)(b * 4096 + n0 + p)) * 64 + o0) = v;
}

// ---------------- upsample conv as 9-tap implicit GEMM, MFMA 16x16x32 bf16
// LDS-staged input rows; co-split x2 via blockIdx.y (n'-half) for occupancy.
__global__ void __launch_bounds__(256)
upconv_mfma_kernel(const unsigned short* __restrict__ X, const unsigned short* __restrict__ Bp,
                   const float* __restrict__ bias, unsigned short* __restrict__ Y,
                   int Hin, int Win) {
    __shared__ __attribute__((aligned(16))) unsigned short sx[3 * 66 * 72];  // 28.5 KB

    int y = blockIdx.y;                 // n'-half (r1 = y)
    int wv = threadIdx.x >> 6;
    int lane = threadIdx.x & 63;
    int q = lane >> 4, n16 = lane & 15;
    int m0 = blockIdx.x * 64;
    int hw = Hin * Win;
    int b = m0 / hw, rem = m0 % hw;
    int h = rem / Win, w0 = rem % Win;
    const unsigned short* Xb = X + (size_t)b * hw * 64;

    // stage 3 rows x 66 px x 64 ch (zero halo), ch-padded to 72
    const us8 z8 = (us8)(unsigned short)0;
    for (int e = threadIdx.x; e < 1584; e += 256) {
        int ch8 = e & 7;
        int pxi = (e >> 3) % 66;
        int row = e / 528;
        int hh = h + row - 1, wp = w0 + pxi - 1;
        us8 v = z8;
        if ((unsigned)hh < (unsigned)Hin && (unsigned)wp < (unsigned)Win)
            v = *(const us8*)(Xb + ((size_t)hh * Win + wp) * 64 + ch8 * 8);
        *(us8*)&sx[row * 4752 + pxi * 72 + ch8 * 8] = v;
    }
    __syncthreads();

    ffrag acc[4][2];
#pragma unroll
    for (int i = 0; i < 4; i++)
#pragma unroll
        for (int j2 = 0; j2 < 2; j2++) acc[i][j2] = (ffrag)0.f;

    int npb = y * 128 + wv * 32;   // n' base for this wave

    for (int t = 0; t < 9; t++) {
        int dy = t / 3, dx = t % 3;
        bfrag af[4][2];
#pragma unroll
        for (int mt = 0; mt < 4; mt++) {
            const unsigned short* sp = &sx[dy * 4752 + (mt * 16 + n16 + dx) * 72 + q * 8];
            af[mt][0] = *(const bfrag*)sp;
            af[mt][1] = *(const bfrag*)(sp + 32);
        }
#pragma unroll
        for (int s = 0; s < 2; s++) {
#pragma unroll
            for (int nt = 0; nt < 2; nt++) {
                bfrag bf = *(const bfrag*)(Bp + (size_t)((((t * 2 + s) * 4 + q) * 256) + npb + nt * 16 + n16) * 8);
#pragma unroll
                for (int mt = 0; mt < 4; mt++)
                    acc[mt][nt] = __builtin_amdgcn_mfma_f32_16x16x32_bf16(af[mt][s], bf, acc[mt][nt], 0, 0, 0);
            }
        }
    }

    int g = y * 2 + (wv >> 1);         // g' = 2*r1 + r2
    int r1 = y, r2 = wv >> 1;
    int cbase = (wv & 1) * 32;
    float bv[2];
#pragma unroll
    for (int nt = 0; nt < 2; nt++) bv[nt] = bias[4 * (cbase + nt * 16 + n16) + g];
    int Wo = Win * 2;
    unsigned short* Yb = Y + ((size_t)b * Hin * 2 * Wo + (size_t)(2 * h + r1) * Wo + r2) * 64;
#pragma unroll
    for (int mt = 0; mt < 4; mt++) {
#pragma unroll
        for (int r = 0; r < 4; r++) {
            int m = mt * 16 + q * 4 + r;   // C/D: row = quad*4 + reg
            unsigned short* dst = Yb + (size_t)(2 * (w0 + m)) * 64;
#pragma unroll
            for (int nt = 0; nt < 2; nt++) {
                float v = acc[mt][nt][r] + bv[nt];
                v = fmaxf(v, 0.f);
                dst[cbase + nt * 16 + n16] = f2bf(v);
            }
        }
    }
}

// ---------------- final conv as 9-tap implicit GEMM, N=16 (3 real), fp32 NCHW out
// 2D tile: 64 px x 4 rows per block; 6 rows x 66 px staged in LDS (57 KB).
__global__ void __launch_bounds__(256)
final_mfma_kernel(const unsigned short* __restrict__ X, const unsigned short* __restrict__ Bp,
                  const float* __restrict__ bias, float* __restrict__ out) {
    __shared__ __attribute__((aligned(16))) unsigned short sx[6 * 66 * 72];  // 57 KB

    int t0 = blockIdx.x;
    int wseg = t0 & 3;
    int rg = (t0 >> 2) & 63;
    int b = t0 >> 8;
    int y0 = rg * 4, w0 = wseg * 64;
    int wv = threadIdx.x >> 6, lane = threadIdx.x & 63;
    int q = lane >> 4, n16 = lane & 15;
    const unsigned short* Xb = X + (size_t)b * 65536 * 64;

    // stage 6 rows x 66 px x 64 ch (zero halo), ch pitch 72
    const us8 z8 = (us8)(unsigned short)0;
    for (int e = threadIdx.x; e < 3168; e += 256) {
        int ch8 = e & 7;
        int pxi = (e >> 3) % 66;
        int row = e / 528;
        int hh = y0 - 1 + row, wp = w0 - 1 + pxi;
        us8 v = z8;
        if ((unsigned)hh < 256u && (unsigned)wp < 256u)
            v = *(const us8*)(Xb + ((size_t)hh * 256 + wp) * 64 + ch8 * 8);
        *(us8*)&sx[row * 4752 + pxi * 72 + ch8 * 8] = v;
    }
    __syncthreads();

    // wave wv handles row y0+wv, 64 px
    ffrag acc[4];
#pragma unroll
    for (int i = 0; i < 4; i++) acc[i] = (ffrag)0.f;

    for (int t = 0; t < 9; t++) {
        int dy = t / 3, dx = t % 3;
        bfrag af[4][2];
#pragma unroll
        for (int mt = 0; mt < 4; mt++) {
            const unsigned short* sp = &sx[(wv + dy) * 4752 + (mt * 16 + n16 + dx) * 72 + q * 8];
            af[mt][0] = *(const bfrag*)sp;
            af[mt][1] = *(const bfrag*)(sp + 32);
        }
#pragma unroll
        for (int s = 0; s < 2; s++) {
            bfrag bf = *(const bfrag*)(Bp + (size_t)((((t * 2 + s) * 4 + q) * 16) + n16) * 8);
#pragma unroll
            for (int mt = 0; mt < 4; mt++)
                acc[mt] = __builtin_amdgcn_mfma_f32_16x16x32_bf16(af[mt][s], bf, acc[mt], 0, 0, 0);
        }
    }

    if (n16 < 3) {
        float bj = bias[n16];
        float* ob = out + (((size_t)b * 3 + n16) * 256 + (y0 + wv)) * 256;
#pragma unroll
        for (int mt = 0; mt < 4; mt++)
#pragma unroll
            for (int r = 0; r < 4; r++)
                ob[w0 + mt * 16 + q * 4 + r] = acc[mt][r] + bj;
    }
}

extern "C" void kernel_launch(void* const* d_in, const int* in_sizes, int n_in,
                              void* d_out, int out_size, void* d_ws, size_t ws_size,
                              hipStream_t stream) {
    const float* x      = (const float*)d_in[0];
    const float* th     = (const float*)d_in[1];
    const float* proj_w = (const float*)d_in[2];
    const float* proj_b = (const float*)d_in[3];
    const float* cf_w   = (const float*)d_in[4];
    const float* cf_b   = (const float*)d_in[5];
    const float* qw     = (const float*)d_in[6];
    const float* qb     = (const float*)d_in[7];
    const float* kw     = (const float*)d_in[8];
    const float* kb     = (const float*)d_in[9];
    const float* vw     = (const float*)d_in[10];
    const float* vb     = (const float*)d_in[11];
    const float* ow     = (const float*)d_in[12];
    const float* ob     = (const float*)d_in[13];
    const float* l1w    = (const float*)d_in[14];
    const float* l1b    = (const float*)d_in[15];
    const float* l2w    = (const float*)d_in[16];
    const float* l2b    = (const float*)d_in[17];
    const float* up_w   = (const float*)d_in[18];
    const float* up_b   = (const float*)d_in[19];
    const float* cl_w   = (const float*)d_in[20];
    const float* cl_b   = (const float*)d_in[21];

    float* ws   = (float*)d_ws;
    float* feat = ws;                         // 2,097,152 f
    float* tf   = feat + 2097152;             // 39,424 f
    float* kbuf = tf + 39424;                 // 630,784 f
    float* vbuf = kbuf + 630784;              // 630,784 f
    unsigned short* X1  = (unsigned short*)(vbuf + 630784);  // 2,097,152 us
    unsigned short* X2  = X1 + 2097152;       // 8,388,608 us
    unsigned short* X3  = X2 + 8388608;       // 33,554,432 us
    unsigned short* PW1 = X3 + 33554432;      // 147,456 us
    unsigned short* PW2 = PW1 + 147456;       // 147,456 us
    unsigned short* PWF = PW2 + 147456;       // 9,216 us
    unsigned short* PQ  = PWF + 9216;         // 65,536 us
    unsigned short* PO  = PQ + 65536;         // 65,536 us

    hipLaunchKernelGGL(prep_kernel, dim3(8192 + 1152 + 36 + 256), dim3(256), 0, stream,
                       x, cf_w, cf_b, feat, up_w, PW1, PW2, cl_w, PWF, qw, ow, PQ, PO);
    hipLaunchKernelGGL(text_proj_kernel, dim3(BATCH * LTXT), dim3(64), 0, stream,
                       th, proj_w, proj_b, tf);
    hipLaunchKernelGGL(kv_all_kernel, dim3(16 * BATCH * LTXT), dim3(64), 0, stream,
                       tf, kw, kb, vw, vb, l2w, l2b, kbuf, vbuf);

    hipLaunchKernelGGL(attn_all_kernel, dim3(BATCH * (HW0 / 64)), dim3(1024), 0, stream,
                       feat, kbuf, vbuf, PQ, PO, qb, ob, l1w, l1b, X1);

    hipLaunchKernelGGL(upconv_mfma_kernel, dim3(BATCH * 64 * 64 / 64, 2), dim3(256), 0, stream,
                       X1, PW1, up_b, X2, 64, 64);
    hipLaunchKernelGGL(upconv_mfma_kernel, dim3(BATCH * 128 * 128 / 64, 2), dim3(256), 0, stream,
                       X2, PW2, up_b + 256, X3, 128, 128);
    hipLaunchKernelGGL(final_mfma_kernel, dim3(BATCH * 64 * 4), dim3(256), 0, stream,
                       X3, PWF, cl_b, (float*)d_out);
}